// Round 4
// baseline (719.357 us; speedup 1.0000x reference)
//
#include <hip/hip_runtime.h>
#include <hip/hip_cooperative_groups.h>
#include <math.h>

namespace cgrp = cooperative_groups;

#define NB 16
#define CIN 64
#define HH 112
#define WW 112
#define HW 12544
#define INIT_C 64
#define NEW_C 64
#define NE 4
#define SE_HIDN 32
#define OUTC 128
#define EPSV 1e-5f
#define TPX 256
#define NT (HW / TPX)   /* 49 */
#define NTILE (NB * NT) /* 784 */
#define GRID 1024
#define CHR 56          /* output rows per dw chunk */
#define SROWS (CHR + 2) /* 58 staged rows */

// ---------------- depthwise helpers ----------------
__device__ __forceinline__ void ldrow(const float* sP, int pr, int cq,
                                      float4& C, float& L, float& R) {
    const float* row = sP + pr * WW;
    C = *(const float4*)(row + cq * 4);
    int lc = cq * 4 - 1;
    lc = lc < 0 ? 0 : lc;
    float lv = row[lc];
    L = (cq == 0) ? 0.f : lv;
    int rc = cq * 4 + 4;
    rc = rc > (WW - 1) ? (WW - 1) : rc;
    float rv = row[rc];
    R = (cq == 27) ? 0.f : rv;
}

__device__ __forceinline__ float4 dw9(const float4 c0, float l0, float r0,
                                      const float4 c1, float l1, float r1,
                                      const float4 c2, float l2, float r2,
                                      const float* K) {
    float4 o;
    o.x = fmaf(K[0], l0, fmaf(K[1], c0.x, fmaf(K[2], c0.y,
          fmaf(K[3], l1, fmaf(K[4], c1.x, fmaf(K[5], c1.y,
          fmaf(K[6], l2, fmaf(K[7], c2.x, K[8] * c2.y))))))));
    o.y = fmaf(K[0], c0.x, fmaf(K[1], c0.y, fmaf(K[2], c0.z,
          fmaf(K[3], c1.x, fmaf(K[4], c1.y, fmaf(K[5], c1.z,
          fmaf(K[6], c2.x, fmaf(K[7], c2.y, K[8] * c2.z))))))));
    o.z = fmaf(K[0], c0.y, fmaf(K[1], c0.z, fmaf(K[2], c0.w,
          fmaf(K[3], c1.y, fmaf(K[4], c1.z, fmaf(K[5], c1.w,
          fmaf(K[6], c2.y, fmaf(K[7], c2.z, K[8] * c2.w))))))));
    o.w = fmaf(K[0], c0.z, fmaf(K[1], c0.w, fmaf(K[2], r0,
          fmaf(K[3], c1.z, fmaf(K[4], c1.w, fmaf(K[5], r1,
          fmaf(K[6], c2.z, fmaf(K[7], c2.w, K[8] * r2))))))));
    return o;
}

// ================= fused cooperative kernel =================
__global__ __launch_bounds__(256, 4) void k_fused(
    const float* x, const float* rw1, const float* rb1, const float* w1,
    const float* bn1_g, const float* bn1_b, const float* bn1_m,
    const float* bn1_v, const float* rw2, const float* rb2, const float* w2,
    const float* bn2_g, const float* bn2_b, const float* bn2_m,
    const float* bn2_v, const float* se_w1, const float* se_b1,
    const float* se_w2, const float* se_b2, float* out, float* pooled,
    float* sum1, float* sum2, float* shift1, float* k1t) {
    cgrp::grid_group grid = cgrp::this_grid();
    __shared__ alignas(16) float sPc[SROWS * WW];  // 25,984 B (also sT in P1)
    __shared__ alignas(16) float srow56[WW];
    __shared__ float sinv[OUTC];
    __shared__ float hvec[SE_HIDN];
    __shared__ float sc4[NE];
    __shared__ float kks[9];
    __shared__ float lred[4];

    int t = threadIdx.x;
    int blk = blockIdx.x;

    // ---------- P0: per-(b,c) mean of x; zero sum1 ----------
    {
        const float4* p4 = (const float4*)(x + (size_t)blk * HW);
        float s = 0.f;
        for (int g = t; g < HW / 4; g += 256) {
            float4 v = p4[g];
            s += v.x + v.y + v.z + v.w;
        }
        for (int off = 32; off > 0; off >>= 1) s += __shfl_down(s, off, 64);
        if ((t & 63) == 0) lred[t >> 6] = s;
        __syncthreads();
        if (t == 0) {
            pooled[blk] = (lred[0] + lred[1] + lred[2] + lred[3]) *
                          (1.f / (float)HW);
            sum1[blk] = 0.f;
        }
    }
    grid.sync();

    // ---------- P1: per-batch mixed 1x1 kernel (blocks 0..15) ----------
    if (blk < NB) {
        int b = blk;
        if (t < NE) {
            float acc = rb1[t];
            const float* pb = pooled + b * CIN;
            const float* rw = rw1 + t * CIN;
            for (int i = 0; i < CIN; i++) acc = fmaf(pb[i], rw[i], acc);
            sc4[t] = 1.f / (1.f + expf(-acc));
        }
        if (t >= 64 && t < 128) {
            int o = t - 64;
            float sc = bn1_g[o] * rsqrtf(bn1_v[o] + EPSV);
            shift1[o] = bn1_b[o] - bn1_m[o] * sc;  // idempotent across blocks
        }
        __syncthreads();
        float* sT = sPc;  // [o][i] padded stride 65
        for (int idx = t; idx < CIN * INIT_C; idx += 256) {
            int o = idx >> 6, i = idx & 63;
            float acc = 0.f;
#pragma unroll
            for (int e = 0; e < NE; e++)
                acc = fmaf(sc4[e], w1[(e * INIT_C + o) * CIN + i], acc);
            float sc = bn1_g[o] * rsqrtf(bn1_v[o] + EPSV);
            sT[o * 65 + i] = acc * sc;
        }
        __syncthreads();
        for (int idx = t; idx < CIN * INIT_C; idx += 256) {
            int i = idx >> 6, o = idx & 63;
            k1t[(b << 12) + idx] = sT[o * 65 + i];  // [i][o], o minor
        }
    }
    grid.sync();

    // ---------- P2: dynamic 1x1 conv (LDS-free streaming) ----------
    for (int task = blk; task < NTILE; task += GRID) {
        int b = task / NT;
        int tile = task - b * NT;
        int p0 = tile * TPX;
        int lane = t & 63;
        int og16 = __builtin_amdgcn_readfirstlane(t >> 6) << 4;
        const float* Aw = k1t + (b << 12) + og16;
        const float* xp = x + (size_t)(b * CIN) * HW + p0 + (lane << 2);
        float4 acc[16];
#pragma unroll
        for (int j = 0; j < 16; j++) acc[j] = make_float4(0.f, 0.f, 0.f, 0.f);
#pragma unroll 2
        for (int i = 0; i < CIN; i++) {
            float4 xv = *(const float4*)(xp + (size_t)i * HW);
#pragma unroll
            for (int j = 0; j < 16; j++) {
                float a = Aw[i * 64 + j];  // wave-uniform -> s_load
                acc[j].x = fmaf(a, xv.x, acc[j].x);
                acc[j].y = fmaf(a, xv.y, acc[j].y);
                acc[j].z = fmaf(a, xv.z, acc[j].z);
                acc[j].w = fmaf(a, xv.w, acc[j].w);
            }
        }
        float* outbase =
            out + ((size_t)(b * OUTC + og16)) * HW + p0 + (lane << 2);
#pragma unroll
        for (int j = 0; j < 16; j++) {
            float sh = shift1[og16 + j];
            float4 r;
            r.x = fmaxf(acc[j].x + sh, 0.f);
            r.y = fmaxf(acc[j].y + sh, 0.f);
            r.z = fmaxf(acc[j].z + sh, 0.f);
            r.w = fmaxf(acc[j].w + sh, 0.f);
            *(float4*)(outbase + (size_t)j * HW) = r;
            float cs = r.x + r.y + r.z + r.w;
            cs += __shfl_xor(cs, 1, 64);
            cs += __shfl_xor(cs, 2, 64);
            cs += __shfl_xor(cs, 4, 64);
            cs += __shfl_xor(cs, 8, 64);
            cs += __shfl_xor(cs, 16, 64);
            cs += __shfl_xor(cs, 32, 64);
            if (lane == 0) atomicAdd(&sum1[b * INIT_C + og16 + j], cs);
        }
    }
    grid.sync();

    // ---------- P3: depthwise sum (x2 never stored) ----------
    int c = blk & 63;
    int b = blk >> 6;
    {
        if (t < NE) {
            float acc = rb2[t];
            const float* s1 = sum1 + b * INIT_C;
            const float* rw = rw2 + t * INIT_C;
            for (int i = 0; i < INIT_C; i++)
                acc = fmaf(s1[i] * (1.f / (float)HW), rw[i], acc);
            sc4[t] = 1.f / (1.f + expf(-acc));
        }
        __syncthreads();
        if (t < 9) {
            float acc = 0.f;
#pragma unroll
            for (int e = 0; e < NE; e++)
                acc = fmaf(sc4[e], w2[(e * NEW_C + c) * 9 + t], acc);
            kks[t] = acc * (bn2_g[c] * rsqrtf(bn2_v[c] + EPSV));
        }
        __syncthreads();
        float sc2 = bn2_g[c] * rsqrtf(bn2_v[c] + EPSV);
        float shift2 = bn2_b[c] - bn2_m[c] * sc2;
        float myk[9];
#pragma unroll
        for (int j = 0; j < 9; j++) myk[j] = kks[j];
        const float* xsrc = out + ((size_t)(b * OUTC + c)) * HW;
        int cq = t & 31, band = t >> 5;
        float csum = 0.f;
        for (int ch = 0; ch < 2; ch++) {
            int h0 = ch * CHR;
            __syncthreads();
            for (int g = t; g < SROWS * 28; g += 256) {
                int r = g / 28, cc = g - r * 28;
                int gr = h0 - 1 + r;
                float4 v = make_float4(0.f, 0.f, 0.f, 0.f);
                if (gr >= 0 && gr < HH)
                    v = *(const float4*)(xsrc + (size_t)gr * WW + (cc << 2));
                ((float4*)sPc)[g] = v;
            }
            __syncthreads();
            if (cq < 28) {
                int j0 = band * 7;
                float4 C[3];
                float L[3], R[3];
                ldrow(sPc, j0, cq, C[0], L[0], R[0]);
                ldrow(sPc, j0 + 1, cq, C[1], L[1], R[1]);
#pragma unroll
                for (int k = 0; k < 7; k++) {
                    int s0 = k % 3, s1i = (k + 1) % 3, s2i = (k + 2) % 3;
                    ldrow(sPc, j0 + k + 2, cq, C[s2i], L[s2i], R[s2i]);
                    float4 o = dw9(C[s0], L[s0], R[s0], C[s1i], L[s1i], R[s1i],
                                   C[s2i], L[s2i], R[s2i], myk);
                    csum += fmaxf(o.x + shift2, 0.f) + fmaxf(o.y + shift2, 0.f) +
                            fmaxf(o.z + shift2, 0.f) + fmaxf(o.w + shift2, 0.f);
                }
            }
        }
        for (int off = 32; off > 0; off >>= 1) csum += __shfl_down(csum, off, 64);
        if ((t & 63) == 0) lred[t >> 6] = csum;
        __syncthreads();
        if (t == 0) sum2[blk] = lred[0] + lred[1] + lred[2] + lred[3];
        // NOTE: chunk1 (global rows 55..112) remains staged in sPc
    }
    grid.sync();

    // ---------- P4: SE gates + dw recompute + gated writes ----------
    {
        int cq = t & 31, band = t >> 5;
        if (t < 64) sinv[t] = sum1[b * 64 + t] * (1.f / (float)HW);
        else if (t < 128) sinv[t] = sum2[b * 64 + (t - 64)] * (1.f / (float)HW);
        // save boundary global row 56 (= retained LDS row 1) before restage
        if (t >= 128 && t < 156)
            ((float4*)srow56)[t - 128] = ((const float4*)(sPc + WW))[t - 128];
        __syncthreads();
        if (t < SE_HIDN) {
            float acc = se_b1[t];
            const float* wrow = se_w1 + t * OUTC;
#pragma unroll 4
            for (int i = 0; i < OUTC; i++) acc = fmaf(sinv[i], wrow[i], acc);
            hvec[t] = fmaxf(acc, 0.f);
        }
        __syncthreads();
        float a1 = se_b2[c], a2 = se_b2[64 + c];
        {
            const float* w2a = se_w2 + c * SE_HIDN;
            const float* w2b = se_w2 + (64 + c) * SE_HIDN;
#pragma unroll 8
            for (int j = 0; j < SE_HIDN; j++) {
                float hj = hvec[j];
                a1 = fmaf(hj, w2a[j], a1);
                a2 = fmaf(hj, w2b[j], a2);
            }
        }
        float s1v = 1.f / (1.f + expf(-a1));
        float s2v = 1.f / (1.f + expf(-a2));
        float sc2 = bn2_g[c] * rsqrtf(bn2_v[c] + EPSV);
        float shift2 = bn2_b[c] - bn2_m[c] * sc2;
        float myk[9];
#pragma unroll
        for (int j = 0; j < 9; j++) myk[j] = kks[j];  // persisted in LDS
        float* d1 = out + ((size_t)(b * OUTC + c)) * HW;
        float* d2 = out + ((size_t)(b * OUTC + 64 + c)) * HW;

        // chunk 1 from retained LDS: output rows 56..111
        if (cq < 28) {
            int j0 = band * 7;
            float4 C[3];
            float L[3], R[3];
            ldrow(sPc, j0, cq, C[0], L[0], R[0]);
            ldrow(sPc, j0 + 1, cq, C[1], L[1], R[1]);
#pragma unroll
            for (int k = 0; k < 7; k++) {
                int s0 = k % 3, s1i = (k + 1) % 3, s2i = (k + 2) % 3;
                ldrow(sPc, j0 + k + 2, cq, C[s2i], L[s2i], R[s2i]);
                float4 o = dw9(C[s0], L[s0], R[s0], C[s1i], L[s1i], R[s1i],
                               C[s2i], L[s2i], R[s2i], myk);
                float4 x1v = C[s1i];
                float4 o1, o2;
                o1.x = x1v.x * s1v; o1.y = x1v.y * s1v;
                o1.z = x1v.z * s1v; o1.w = x1v.w * s1v;
                o2.x = fmaxf(o.x + shift2, 0.f) * s2v;
                o2.y = fmaxf(o.y + shift2, 0.f) * s2v;
                o2.z = fmaxf(o.z + shift2, 0.f) * s2v;
                o2.w = fmaxf(o.w + shift2, 0.f) * s2v;
                int row = CHR + j0 + k;
                *(float4*)(d1 + (size_t)row * WW + cq * 4) = o1;
                *(float4*)(d2 + (size_t)row * WW + cq * 4) = o2;
            }
        }
        __syncthreads();
        // restage chunk 0 (rows -1..56; rows 0..55 pristine, 56 from srow56)
        for (int g = t; g < SROWS * 28; g += 256) {
            int r = g / 28, cc = g - r * 28;
            int gr = r - 1;
            float4 v = make_float4(0.f, 0.f, 0.f, 0.f);
            if (gr >= 0 && gr < CHR)
                v = *(const float4*)(d1 + (size_t)gr * WW + (cc << 2));
            else if (gr == CHR)
                v = ((const float4*)srow56)[cc];
            ((float4*)sPc)[g] = v;
        }
        __syncthreads();
        if (cq < 28) {
            int j0 = band * 7;
            float4 C[3];
            float L[3], R[3];
            ldrow(sPc, j0, cq, C[0], L[0], R[0]);
            ldrow(sPc, j0 + 1, cq, C[1], L[1], R[1]);
#pragma unroll
            for (int k = 0; k < 7; k++) {
                int s0 = k % 3, s1i = (k + 1) % 3, s2i = (k + 2) % 3;
                ldrow(sPc, j0 + k + 2, cq, C[s2i], L[s2i], R[s2i]);
                float4 o = dw9(C[s0], L[s0], R[s0], C[s1i], L[s1i], R[s1i],
                               C[s2i], L[s2i], R[s2i], myk);
                float4 x1v = C[s1i];
                float4 o1, o2;
                o1.x = x1v.x * s1v; o1.y = x1v.y * s1v;
                o1.z = x1v.z * s1v; o1.w = x1v.w * s1v;
                o2.x = fmaxf(o.x + shift2, 0.f) * s2v;
                o2.y = fmaxf(o.y + shift2, 0.f) * s2v;
                o2.z = fmaxf(o.z + shift2, 0.f) * s2v;
                o2.w = fmaxf(o.w + shift2, 0.f) * s2v;
                int row = j0 + k;
                *(float4*)(d1 + (size_t)row * WW + cq * 4) = o1;
                *(float4*)(d2 + (size_t)row * WW + cq * 4) = o2;
            }
        }
    }
}

// ================= fallback 5-kernel path (R3, known-good) =================
__global__ __launch_bounds__(256) void k_pool(const float* __restrict__ x,
                                              float* __restrict__ pooled,
                                              float* __restrict__ sum1) {
    int bc = blockIdx.x;
    const float4* p4 = (const float4*)(x + (size_t)bc * HW);
    float s = 0.f;
    for (int g = threadIdx.x; g < HW / 4; g += 256) {
        float4 v = p4[g];
        s += v.x + v.y + v.z + v.w;
    }
    for (int off = 32; off > 0; off >>= 1) s += __shfl_down(s, off, 64);
    __shared__ float ls[4];
    if ((threadIdx.x & 63) == 0) ls[threadIdx.x >> 6] = s;
    __syncthreads();
    if (threadIdx.x == 0) {
        pooled[bc] = (ls[0] + ls[1] + ls[2] + ls[3]) * (1.f / (float)HW);
        sum1[bc] = 0.f;
    }
}

__global__ __launch_bounds__(256) void k_prep(
    const float* __restrict__ pooled, const float* __restrict__ rw1,
    const float* __restrict__ rb1, const float* __restrict__ w1,
    const float* __restrict__ bn1_g, const float* __restrict__ bn1_b,
    const float* __restrict__ bn1_m, const float* __restrict__ bn1_v,
    float* __restrict__ k1t, float* __restrict__ shift1) {
    int b = blockIdx.x;
    int t = threadIdx.x;
    __shared__ float r1s[NE];
    __shared__ float sT[64][65];
    if (t < NE) {
        float acc = rb1[t];
        const float* pb = pooled + b * CIN;
        const float* rw = rw1 + t * CIN;
        for (int i = 0; i < CIN; i++) acc = fmaf(pb[i], rw[i], acc);
        r1s[t] = 1.f / (1.f + expf(-acc));
    }
    if (t >= 64 && t < 128) {
        int o = t - 64;
        float sc = bn1_g[o] * rsqrtf(bn1_v[o] + EPSV);
        shift1[o] = bn1_b[o] - bn1_m[o] * sc;
    }
    __syncthreads();
    for (int idx = t; idx < CIN * INIT_C; idx += 256) {
        int o = idx >> 6, i = idx & 63;
        float acc = 0.f;
#pragma unroll
        for (int e = 0; e < NE; e++)
            acc = fmaf(r1s[e], w1[(e * INIT_C + o) * CIN + i], acc);
        float sc = bn1_g[o] * rsqrtf(bn1_v[o] + EPSV);
        sT[o][i] = acc * sc;
    }
    __syncthreads();
    for (int idx = t; idx < CIN * INIT_C; idx += 256) {
        int i = idx >> 6, o = idx & 63;
        k1t[(b << 12) + idx] = sT[o][i];
    }
}

__global__ __launch_bounds__(256, 4) void k_conv1(
    const float* __restrict__ x, const float* __restrict__ k1t,
    const float* __restrict__ shift1, float* __restrict__ out,
    float* __restrict__ sum1) {
    int b = blockIdx.x / NT;
    int tile = blockIdx.x - b * NT;
    int p0 = tile * TPX;
    int t = threadIdx.x;
    int lane = t & 63;
    int og16 = __builtin_amdgcn_readfirstlane(t >> 6) << 4;
    const float* Aw = k1t + (b << 12) + og16;
    const float* xp = x + (size_t)(b * CIN) * HW + p0 + (lane << 2);
    float4 acc[16];
#pragma unroll
    for (int j = 0; j < 16; j++) acc[j] = make_float4(0.f, 0.f, 0.f, 0.f);
#pragma unroll 2
    for (int i = 0; i < CIN; i++) {
        float4 xv = *(const float4*)(xp + (size_t)i * HW);
#pragma unroll
        for (int j = 0; j < 16; j++) {
            float a = Aw[i * 64 + j];
            acc[j].x = fmaf(a, xv.x, acc[j].x);
            acc[j].y = fmaf(a, xv.y, acc[j].y);
            acc[j].z = fmaf(a, xv.z, acc[j].z);
            acc[j].w = fmaf(a, xv.w, acc[j].w);
        }
    }
    float* outbase = out + ((size_t)(b * OUTC + og16)) * HW + p0 + (lane << 2);
#pragma unroll
    for (int j = 0; j < 16; j++) {
        float sh = shift1[og16 + j];
        float4 r;
        r.x = fmaxf(acc[j].x + sh, 0.f);
        r.y = fmaxf(acc[j].y + sh, 0.f);
        r.z = fmaxf(acc[j].z + sh, 0.f);
        r.w = fmaxf(acc[j].w + sh, 0.f);
        *(float4*)(outbase + (size_t)j * HW) = r;
        float cs = r.x + r.y + r.z + r.w;
        cs += __shfl_xor(cs, 1, 64);
        cs += __shfl_xor(cs, 2, 64);
        cs += __shfl_xor(cs, 4, 64);
        cs += __shfl_xor(cs, 8, 64);
        cs += __shfl_xor(cs, 16, 64);
        cs += __shfl_xor(cs, 32, 64);
        if (lane == 0) atomicAdd(&sum1[b * INIT_C + og16 + j], cs);
    }
}

#define PROWS (HH + 2)

__global__ __launch_bounds__(256) void k_dwsum(
    const float* __restrict__ xin, const float* __restrict__ sum1,
    const float* __restrict__ rw2, const float* __restrict__ rb2,
    const float* __restrict__ w2, const float* __restrict__ bn2_g,
    const float* __restrict__ bn2_b, const float* __restrict__ bn2_m,
    const float* __restrict__ bn2_v, float* __restrict__ sum2) {
    __shared__ alignas(16) float sP[PROWS * WW];
    __shared__ float r2s[NE];
    __shared__ float kks[9];
    int c = blockIdx.x & 63;
    int b = blockIdx.x >> 6;
    int t = threadIdx.x;
    if (t < NE) {
        float acc = rb2[t];
        const float* s1 = sum1 + b * INIT_C;
        const float* rw = rw2 + t * INIT_C;
        for (int i = 0; i < INIT_C; i++)
            acc = fmaf(s1[i] * (1.f / (float)HW), rw[i], acc);
        r2s[t] = 1.f / (1.f + expf(-acc));
    }
    if (t < WW / 4) {
        float4 z = {0.f, 0.f, 0.f, 0.f};
        ((float4*)sP)[t] = z;
        ((float4*)(sP + (PROWS - 1) * WW))[t] = z;
    }
    __syncthreads();
    if (t < 9) {
        float acc = 0.f;
#pragma unroll
        for (int e = 0; e < NE; e++)
            acc = fmaf(r2s[e], w2[(e * NEW_C + c) * 9 + t], acc);
        kks[t] = acc * (bn2_g[c] * rsqrtf(bn2_v[c] + EPSV));
    }
    const float4* src4 = (const float4*)(xin + ((size_t)(b * OUTC + c)) * HW);
    float4* dst4 = (float4*)(sP + WW);
    for (int g = t; g < HW / 4; g += 256) dst4[g] = src4[g];
    __syncthreads();
    float sc2 = bn2_g[c] * rsqrtf(bn2_v[c] + EPSV);
    float shift = bn2_b[c] - bn2_m[c] * sc2;
    float myk[9];
#pragma unroll
    for (int j = 0; j < 9; j++) myk[j] = kks[j];
    int cq = t & 31;
    int band = t >> 5;
    float csum = 0.f;
    if (cq < 28) {
        int pr0 = band * 14;
        float4 C[3];
        float L[3], R[3];
        ldrow(sP, pr0, cq, C[0], L[0], R[0]);
        ldrow(sP, pr0 + 1, cq, C[1], L[1], R[1]);
#pragma unroll
        for (int k = 0; k < 14; k++) {
            int s0 = k % 3, s1 = (k + 1) % 3, s2 = (k + 2) % 3;
            ldrow(sP, pr0 + k + 2, cq, C[s2], L[s2], R[s2]);
            float4 o = dw9(C[s0], L[s0], R[s0], C[s1], L[s1], R[s1], C[s2],
                           L[s2], R[s2], myk);
            csum += fmaxf(o.x + shift, 0.f) + fmaxf(o.y + shift, 0.f) +
                    fmaxf(o.z + shift, 0.f) + fmaxf(o.w + shift, 0.f);
        }
    }
    for (int off = 32; off > 0; off >>= 1) csum += __shfl_down(csum, off, 64);
    __shared__ float ls[4];
    if ((t & 63) == 0) ls[t >> 6] = csum;
    __syncthreads();
    if (t == 0) sum2[b * NEW_C + c] = ls[0] + ls[1] + ls[2] + ls[3];
}

__global__ __launch_bounds__(256) void k_final(
    const float* __restrict__ xin, const float* __restrict__ sum1,
    const float* __restrict__ sum2, const float* __restrict__ rw2,
    const float* __restrict__ rb2, const float* __restrict__ w2,
    const float* __restrict__ bn2_g, const float* __restrict__ bn2_b,
    const float* __restrict__ bn2_m, const float* __restrict__ bn2_v,
    const float* __restrict__ se_w1, const float* __restrict__ se_b1,
    const float* __restrict__ se_w2, const float* __restrict__ se_b2,
    float* __restrict__ out) {
    __shared__ alignas(16) float sP[PROWS * WW];
    __shared__ float sin_[OUTC];
    __shared__ float hvec[SE_HIDN];
    __shared__ float r2s[NE];
    __shared__ float kks[9];
    int c = blockIdx.x & 63;
    int b = blockIdx.x >> 6;
    int t = threadIdx.x;
    if (t < 64) sin_[t] = sum1[b * 64 + t] * (1.f / (float)HW);
    else if (t < 128) sin_[t] = sum2[b * 64 + (t - 64)] * (1.f / (float)HW);
    if (t >= 128 && t < 128 + NE) {
        int e = t - 128;
        float acc = rb2[e];
        const float* s1 = sum1 + b * INIT_C;
        const float* rw = rw2 + e * INIT_C;
        for (int i = 0; i < INIT_C; i++)
            acc = fmaf(s1[i] * (1.f / (float)HW), rw[i], acc);
        r2s[e] = 1.f / (1.f + expf(-acc));
    }
    if (t >= 160 && t < 160 + WW / 4) {
        float4 z = {0.f, 0.f, 0.f, 0.f};
        ((float4*)sP)[t - 160] = z;
        ((float4*)(sP + (PROWS - 1) * WW))[t - 160] = z;
    }
    __syncthreads();
    if (t < SE_HIDN) {
        float acc = se_b1[t];
        const float* wrow = se_w1 + t * OUTC;
#pragma unroll 4
        for (int i = 0; i < OUTC; i++) acc = fmaf(sin_[i], wrow[i], acc);
        hvec[t] = fmaxf(acc, 0.f);
    }
    if (t >= 64 && t < 73) {
        int j = t - 64;
        float acc = 0.f;
#pragma unroll
        for (int e = 0; e < NE; e++)
            acc = fmaf(r2s[e], w2[(e * NEW_C + c) * 9 + j], acc);
        kks[j] = acc * (bn2_g[c] * rsqrtf(bn2_v[c] + EPSV));
    }
    const float4* src4 = (const float4*)(xin + ((size_t)(b * OUTC + c)) * HW);
    float4* pdst4 = (float4*)(sP + WW);
    for (int g = t; g < HW / 4; g += 256) pdst4[g] = src4[g];
    __syncthreads();
    float a1 = se_b2[c], a2 = se_b2[64 + c];
    {
        const float* w2a = se_w2 + c * SE_HIDN;
        const float* w2b = se_w2 + (64 + c) * SE_HIDN;
#pragma unroll 8
        for (int j = 0; j < SE_HIDN; j++) {
            float hj = hvec[j];
            a1 = fmaf(hj, w2a[j], a1);
            a2 = fmaf(hj, w2b[j], a2);
        }
    }
    float s1v = 1.f / (1.f + expf(-a1));
    float s2v = 1.f / (1.f + expf(-a2));
    float sc2 = bn2_g[c] * rsqrtf(bn2_v[c] + EPSV);
    float shift = bn2_b[c] - bn2_m[c] * sc2;
    float myk[9];
#pragma unroll
    for (int j = 0; j < 9; j++) myk[j] = kks[j];
    int cq = t & 31;
    int band = t >> 5;
    if (cq < 28) {
        float* d1 = out + ((size_t)(b * OUTC + c)) * HW;
        float* d2 = out + ((size_t)(b * OUTC + 64 + c)) * HW;
        int pr0 = band * 14;
        float4 C[3];
        float L[3], R[3];
        ldrow(sP, pr0, cq, C[0], L[0], R[0]);
        ldrow(sP, pr0 + 1, cq, C[1], L[1], R[1]);
#pragma unroll
        for (int k = 0; k < 14; k++) {
            int s0 = k % 3, s1 = (k + 1) % 3, s2 = (k + 2) % 3;
            ldrow(sP, pr0 + k + 2, cq, C[s2], L[s2], R[s2]);
            float4 o = dw9(C[s0], L[s0], R[s0], C[s1], L[s1], R[s1], C[s2],
                           L[s2], R[s2], myk);
            float4 x1v = C[s1];
            float4 o1, o2;
            o1.x = x1v.x * s1v; o1.y = x1v.y * s1v;
            o1.z = x1v.z * s1v; o1.w = x1v.w * s1v;
            o2.x = fmaxf(o.x + shift, 0.f) * s2v;
            o2.y = fmaxf(o.y + shift, 0.f) * s2v;
            o2.z = fmaxf(o.z + shift, 0.f) * s2v;
            o2.w = fmaxf(o.w + shift, 0.f) * s2v;
            int row = band * 14 + k;
            *(float4*)(d1 + (size_t)row * WW + cq * 4) = o1;
            *(float4*)(d2 + (size_t)row * WW + cq * 4) = o2;
        }
    }
}

extern "C" void kernel_launch(void* const* d_in, const int* in_sizes, int n_in,
                              void* d_out, int out_size, void* d_ws,
                              size_t ws_size, hipStream_t stream) {
    (void)in_sizes; (void)n_in; (void)out_size; (void)ws_size;
    const float* x = (const float*)d_in[0];
    const float* rw1 = (const float*)d_in[1];
    const float* rb1 = (const float*)d_in[2];
    const float* w1 = (const float*)d_in[3];
    const float* bn1_g = (const float*)d_in[4];
    const float* bn1_b = (const float*)d_in[5];
    const float* bn1_m = (const float*)d_in[6];
    const float* bn1_v = (const float*)d_in[7];
    const float* rw2 = (const float*)d_in[8];
    const float* rb2 = (const float*)d_in[9];
    const float* w2 = (const float*)d_in[10];
    const float* bn2_g = (const float*)d_in[11];
    const float* bn2_b = (const float*)d_in[12];
    const float* bn2_m = (const float*)d_in[13];
    const float* bn2_v = (const float*)d_in[14];
    const float* se_w1 = (const float*)d_in[15];
    const float* se_b1 = (const float*)d_in[16];
    const float* se_w2 = (const float*)d_in[17];
    const float* se_b2 = (const float*)d_in[18];
    float* out = (float*)d_out;
    float* ws = (float*)d_ws;
    float* pooled = ws;
    float* sum1 = ws + 1024;
    float* sum2 = ws + 2048;
    float* shift1 = ws + 3072;
    float* k1t = ws + 4096;

    void* kargs[] = {
        (void*)&x,     (void*)&rw1,   (void*)&rb1,    (void*)&w1,
        (void*)&bn1_g, (void*)&bn1_b, (void*)&bn1_m,  (void*)&bn1_v,
        (void*)&rw2,   (void*)&rb2,   (void*)&w2,     (void*)&bn2_g,
        (void*)&bn2_b, (void*)&bn2_m, (void*)&bn2_v,  (void*)&se_w1,
        (void*)&se_b1, (void*)&se_w2, (void*)&se_b2,  (void*)&out,
        (void*)&pooled,(void*)&sum1,  (void*)&sum2,   (void*)&shift1,
        (void*)&k1t};
    hipError_t e = hipLaunchCooperativeKernel((void*)k_fused, dim3(GRID),
                                              dim3(256), kargs, 0, stream);
    if (e != hipSuccess) {
        // fallback: known-good 5-kernel path
        k_pool<<<NB * CIN, 256, 0, stream>>>(x, pooled, sum1);
        k_prep<<<NB, 256, 0, stream>>>(pooled, rw1, rb1, w1, bn1_g, bn1_b,
                                       bn1_m, bn1_v, k1t, shift1);
        k_conv1<<<NB * NT, 256, 0, stream>>>(x, k1t, shift1, out, sum1);
        k_dwsum<<<NB * NEW_C, 256, 0, stream>>>(out, sum1, rw2, rb2, w2, bn2_g,
                                                bn2_b, bn2_m, bn2_v, sum2);
        k_final<<<NB * NEW_C, 256, 0, stream>>>(out, sum1, sum2, rw2, rb2, w2,
                                                bn2_g, bn2_b, bn2_m, bn2_v,
                                                se_w1, se_b1, se_w2, se_b2, out);
    }
}

// Round 6
// 279.495 us; speedup vs baseline: 2.5738x; 2.5738x over previous
//
#include <hip/hip_runtime.h>
#include <math.h>

#define NB 16
#define CIN 64
#define HH 112
#define WW 112
#define HW 12544
#define INIT_C 64
#define NEW_C 64
#define NE 4
#define SE_HIDN 32
#define OUTC 128
#define EPSV 1e-5f
#define TPX 256
#define NT (HW / TPX)   /* 49 */
#define CHR 56          /* output rows per dw chunk */
#define SROWS (CHR + 2) /* 58 staged rows, 26 KB */

typedef float nf4 __attribute__((ext_vector_type(4)));

__device__ __forceinline__ void nt_store4(float* p, float a, float b, float c,
                                          float d) {
    nf4 v = {a, b, c, d};
    __builtin_nontemporal_store(v, (nf4*)p);
}

// ---------------- kernel 1: pooled mean of x, zero sum1 ----------------
__global__ __launch_bounds__(256) void k_pool(const float* __restrict__ x,
                                              float* __restrict__ pooled,
                                              float* __restrict__ sum1) {
    int bc = blockIdx.x;
    const float4* p4 = (const float4*)(x + (size_t)bc * HW);
    float s = 0.f;
    for (int g = threadIdx.x; g < HW / 4; g += 256) {
        float4 v = p4[g];
        s += v.x + v.y + v.z + v.w;
    }
    for (int off = 32; off > 0; off >>= 1) s += __shfl_down(s, off, 64);
    __shared__ float ls[4];
    if ((threadIdx.x & 63) == 0) ls[threadIdx.x >> 6] = s;
    __syncthreads();
    if (threadIdx.x == 0) {
        pooled[bc] = (ls[0] + ls[1] + ls[2] + ls[3]) * (1.f / (float)HW);
        sum1[bc] = 0.f;
    }
}

// ---------------- kernel 1b: per-batch mixed 1x1 kernel, BN folded ----------------
__global__ __launch_bounds__(256) void k_prep(
    const float* __restrict__ pooled, const float* __restrict__ rw1,
    const float* __restrict__ rb1, const float* __restrict__ w1,
    const float* __restrict__ bn1_g, const float* __restrict__ bn1_b,
    const float* __restrict__ bn1_m, const float* __restrict__ bn1_v,
    float* __restrict__ k1t, float* __restrict__ shift1) {
    int b = blockIdx.x;
    int t = threadIdx.x;
    __shared__ float r1s[NE];
    __shared__ float sT[64][65];
    if (t < NE) {
        float acc = rb1[t];
        const float* pb = pooled + b * CIN;
        const float* rw = rw1 + t * CIN;
        for (int i = 0; i < CIN; i++) acc = fmaf(pb[i], rw[i], acc);
        r1s[t] = 1.f / (1.f + expf(-acc));
    }
    if (t >= 64 && t < 128) {
        int o = t - 64;
        float sc = bn1_g[o] * rsqrtf(bn1_v[o] + EPSV);
        shift1[o] = bn1_b[o] - bn1_m[o] * sc;
    }
    __syncthreads();
    for (int idx = t; idx < CIN * INIT_C; idx += 256) {
        int o = idx >> 6, i = idx & 63;
        float acc = 0.f;
#pragma unroll
        for (int e = 0; e < NE; e++)
            acc = fmaf(r1s[e], w1[(e * INIT_C + o) * CIN + i], acc);
        float sc = bn1_g[o] * rsqrtf(bn1_v[o] + EPSV);
        sT[o][i] = acc * sc;
    }
    __syncthreads();
    for (int idx = t; idx < CIN * INIT_C; idx += 256) {
        int i = idx >> 6, o = idx & 63;
        k1t[(b << 12) + idx] = sT[o][i];
    }
}

// ---------------- kernel 2: dynamic 1x1 conv, LDS-free streaming ----------------
__global__ __launch_bounds__(256, 4) void k_conv1(
    const float* __restrict__ x, const float* __restrict__ k1t,
    const float* __restrict__ shift1, float* __restrict__ out,
    float* __restrict__ sum1) {
    int b = blockIdx.x / NT;
    int tile = blockIdx.x - b * NT;
    int p0 = tile * TPX;
    int t = threadIdx.x;
    int lane = t & 63;
    int og16 = __builtin_amdgcn_readfirstlane(t >> 6) << 4;
    const float* Aw = k1t + (b << 12) + og16;
    const float* xp = x + (size_t)(b * CIN) * HW + p0 + (lane << 2);
    float4 acc[16];
#pragma unroll
    for (int j = 0; j < 16; j++) acc[j] = make_float4(0.f, 0.f, 0.f, 0.f);
#pragma unroll 4
    for (int i = 0; i < CIN; i++) {
        float4 xv = *(const float4*)(xp + (size_t)i * HW);
#pragma unroll
        for (int j = 0; j < 16; j++) {
            float a = Aw[i * 64 + j];  // wave-uniform -> s_load
            acc[j].x = fmaf(a, xv.x, acc[j].x);
            acc[j].y = fmaf(a, xv.y, acc[j].y);
            acc[j].z = fmaf(a, xv.z, acc[j].z);
            acc[j].w = fmaf(a, xv.w, acc[j].w);
        }
    }
    float* outbase = out + ((size_t)(b * OUTC + og16)) * HW + p0 + (lane << 2);
#pragma unroll
    for (int j = 0; j < 16; j++) {
        float sh = shift1[og16 + j];
        float4 r;
        r.x = fmaxf(acc[j].x + sh, 0.f);
        r.y = fmaxf(acc[j].y + sh, 0.f);
        r.z = fmaxf(acc[j].z + sh, 0.f);
        r.w = fmaxf(acc[j].w + sh, 0.f);
        *(float4*)(outbase + (size_t)j * HW) = r;
        float cs = r.x + r.y + r.z + r.w;
        cs += __shfl_xor(cs, 1, 64);
        cs += __shfl_xor(cs, 2, 64);
        cs += __shfl_xor(cs, 4, 64);
        cs += __shfl_xor(cs, 8, 64);
        cs += __shfl_xor(cs, 16, 64);
        cs += __shfl_xor(cs, 32, 64);
        if (lane == 0) atomicAdd(&sum1[b * INIT_C + og16 + j], cs);
    }
}

// ---------------- depthwise helpers ----------------
__device__ __forceinline__ void ldrow(const float* sP, int pr, int cq,
                                      float4& C, float& L, float& R) {
    const float* row = sP + pr * WW;
    C = *(const float4*)(row + cq * 4);
    int lc = cq * 4 - 1;
    lc = lc < 0 ? 0 : lc;
    float lv = row[lc];
    L = (cq == 0) ? 0.f : lv;
    int rc = cq * 4 + 4;
    rc = rc > (WW - 1) ? (WW - 1) : rc;
    float rv = row[rc];
    R = (cq == 27) ? 0.f : rv;
}

__device__ __forceinline__ float4 dw9(const float4 c0, float l0, float r0,
                                      const float4 c1, float l1, float r1,
                                      const float4 c2, float l2, float r2,
                                      const float* K) {
    float4 o;
    o.x = fmaf(K[0], l0, fmaf(K[1], c0.x, fmaf(K[2], c0.y,
          fmaf(K[3], l1, fmaf(K[4], c1.x, fmaf(K[5], c1.y,
          fmaf(K[6], l2, fmaf(K[7], c2.x, K[8] * c2.y))))))));
    o.y = fmaf(K[0], c0.x, fmaf(K[1], c0.y, fmaf(K[2], c0.z,
          fmaf(K[3], c1.x, fmaf(K[4], c1.y, fmaf(K[5], c1.z,
          fmaf(K[6], c2.x, fmaf(K[7], c2.y, K[8] * c2.z))))))));
    o.z = fmaf(K[0], c0.y, fmaf(K[1], c0.z, fmaf(K[2], c0.w,
          fmaf(K[3], c1.y, fmaf(K[4], c1.z, fmaf(K[5], c1.w,
          fmaf(K[6], c2.y, fmaf(K[7], c2.z, K[8] * c2.w))))))));
    o.w = fmaf(K[0], c0.z, fmaf(K[1], c0.w, fmaf(K[2], r0,
          fmaf(K[3], c1.z, fmaf(K[4], c1.w, fmaf(K[5], r1,
          fmaf(K[6], c2.z, fmaf(K[7], c2.w, K[8] * r2))))))));
    return o;
}

// ---------------- kernel 3: dw 3x3 + BN2 + ReLU -> sum2, two 26KB chunks ----------------
__global__ __launch_bounds__(256) void k_dwsum(
    const float* __restrict__ xin, const float* __restrict__ sum1,
    const float* __restrict__ rw2, const float* __restrict__ rb2,
    const float* __restrict__ w2, const float* __restrict__ bn2_g,
    const float* __restrict__ bn2_b, const float* __restrict__ bn2_m,
    const float* __restrict__ bn2_v, float* __restrict__ sum2) {
    __shared__ alignas(16) float sP[SROWS * WW];  // 25,984 B
    __shared__ float r2s[NE];
    __shared__ float kks[9];
    __shared__ float lred[4];
    int c = blockIdx.x & 63;
    int b = blockIdx.x >> 6;
    int t = threadIdx.x;

    if (t < NE) {
        float acc = rb2[t];
        const float* s1 = sum1 + b * INIT_C;
        const float* rw = rw2 + t * INIT_C;
        for (int i = 0; i < INIT_C; i++)
            acc = fmaf(s1[i] * (1.f / (float)HW), rw[i], acc);
        r2s[t] = 1.f / (1.f + expf(-acc));
    }
    __syncthreads();
    if (t < 9) {
        float acc = 0.f;
#pragma unroll
        for (int e = 0; e < NE; e++)
            acc = fmaf(r2s[e], w2[(e * NEW_C + c) * 9 + t], acc);
        kks[t] = acc * (bn2_g[c] * rsqrtf(bn2_v[c] + EPSV));
    }
    __syncthreads();
    float sc2 = bn2_g[c] * rsqrtf(bn2_v[c] + EPSV);
    float shift2 = bn2_b[c] - bn2_m[c] * sc2;
    float myk[9];
#pragma unroll
    for (int j = 0; j < 9; j++) myk[j] = kks[j];

    const float* xsrc = xin + ((size_t)(b * OUTC + c)) * HW;
    int cq = t & 31, band = t >> 5;
    float csum = 0.f;
    for (int ch = 0; ch < 2; ch++) {
        int h0 = ch * CHR;
        __syncthreads();
        for (int g = t; g < SROWS * 28; g += 256) {
            int r = g / 28, cc = g - r * 28;
            int gr = h0 - 1 + r;
            float4 v = make_float4(0.f, 0.f, 0.f, 0.f);
            if (gr >= 0 && gr < HH)
                v = *(const float4*)(xsrc + (size_t)gr * WW + (cc << 2));
            ((float4*)sP)[g] = v;
        }
        __syncthreads();
        if (cq < 28) {
            int j0 = band * 7;
            float4 C[3];
            float L[3], R[3];
            ldrow(sP, j0, cq, C[0], L[0], R[0]);
            ldrow(sP, j0 + 1, cq, C[1], L[1], R[1]);
#pragma unroll
            for (int k = 0; k < 7; k++) {
                int s0 = k % 3, s1i = (k + 1) % 3, s2i = (k + 2) % 3;
                ldrow(sP, j0 + k + 2, cq, C[s2i], L[s2i], R[s2i]);
                float4 o = dw9(C[s0], L[s0], R[s0], C[s1i], L[s1i], R[s1i],
                               C[s2i], L[s2i], R[s2i], myk);
                csum += fmaxf(o.x + shift2, 0.f) + fmaxf(o.y + shift2, 0.f) +
                        fmaxf(o.z + shift2, 0.f) + fmaxf(o.w + shift2, 0.f);
            }
        }
    }
    for (int off = 32; off > 0; off >>= 1) csum += __shfl_down(csum, off, 64);
    if ((t & 63) == 0) lred[t >> 6] = csum;
    __syncthreads();
    if (t == 0) sum2[blockIdx.x] = lred[0] + lred[1] + lred[2] + lred[3];
}

// ---------------- kernel 4: SE gate + dw recompute + gated writes, two chunks ----------------
__global__ __launch_bounds__(256) void k_final(
    const float* __restrict__ sum1, const float* __restrict__ sum2,
    const float* __restrict__ rw2, const float* __restrict__ rb2,
    const float* __restrict__ w2, const float* __restrict__ bn2_g,
    const float* __restrict__ bn2_b, const float* __restrict__ bn2_m,
    const float* __restrict__ bn2_v, const float* __restrict__ se_w1,
    const float* __restrict__ se_b1, const float* __restrict__ se_w2,
    const float* __restrict__ se_b2, float* __restrict__ out) {
    __shared__ alignas(16) float sP[SROWS * WW];
    __shared__ alignas(16) float srow56[WW];
    __shared__ float sinv[OUTC];
    __shared__ float hvec[SE_HIDN];
    __shared__ float r2s[NE];
    __shared__ float kks[9];
    int c = blockIdx.x & 63;
    int b = blockIdx.x >> 6;
    int t = threadIdx.x;

    // phase A: SE input vector + r2
    if (t < 64) sinv[t] = sum1[b * 64 + t] * (1.f / (float)HW);
    else if (t < 128) sinv[t] = sum2[b * 64 + (t - 64)] * (1.f / (float)HW);
    if (t >= 128 && t < 128 + NE) {
        int e = t - 128;
        float acc = rb2[e];
        const float* s1 = sum1 + b * INIT_C;
        const float* rw = rw2 + e * INIT_C;
        for (int i = 0; i < INIT_C; i++)
            acc = fmaf(s1[i] * (1.f / (float)HW), rw[i], acc);
        r2s[e] = 1.f / (1.f + expf(-acc));
    }
    __syncthreads();
    // phase B: hidden layer, dw coeffs, stage chunk1 (x1 rows 55..112)
    if (t < SE_HIDN) {
        float acc = se_b1[t];
        const float* wrow = se_w1 + t * OUTC;
#pragma unroll 4
        for (int i = 0; i < OUTC; i++) acc = fmaf(sinv[i], wrow[i], acc);
        hvec[t] = fmaxf(acc, 0.f);
    }
    if (t >= 64 && t < 73) {
        int j = t - 64;
        float acc = 0.f;
#pragma unroll
        for (int e = 0; e < NE; e++)
            acc = fmaf(r2s[e], w2[(e * NEW_C + c) * 9 + j], acc);
        kks[j] = acc * (bn2_g[c] * rsqrtf(bn2_v[c] + EPSV));
    }
    float* d1 = out + ((size_t)(b * OUTC + c)) * HW;
    float* d2 = out + ((size_t)(b * OUTC + 64 + c)) * HW;
    for (int g = t; g < SROWS * 28; g += 256) {
        int r = g / 28, cc = g - r * 28;
        int gr = CHR - 1 + r;  // 55..112
        float4 v = make_float4(0.f, 0.f, 0.f, 0.f);
        if (gr < HH) v = *(const float4*)(d1 + (size_t)gr * WW + (cc << 2));
        ((float4*)sP)[g] = v;
    }
    __syncthreads();
    // phase C: gates (redundant per thread), save boundary row 56
    if (t < 28) ((float4*)srow56)[t] = ((const float4*)(sP + WW))[t];
    float a1 = se_b2[c], a2 = se_b2[64 + c];
    {
        const float* w2a = se_w2 + c * SE_HIDN;
        const float* w2b = se_w2 + (64 + c) * SE_HIDN;
#pragma unroll 8
        for (int j = 0; j < SE_HIDN; j++) {
            float hj = hvec[j];
            a1 = fmaf(hj, w2a[j], a1);
            a2 = fmaf(hj, w2b[j], a2);
        }
    }
    float s1v = 1.f / (1.f + expf(-a1));
    float s2v = 1.f / (1.f + expf(-a2));
    float sc2 = bn2_g[c] * rsqrtf(bn2_v[c] + EPSV);
    float shift2 = bn2_b[c] - bn2_m[c] * sc2;
    float myk[9];
#pragma unroll
    for (int j = 0; j < 9; j++) myk[j] = kks[j];

    int cq = t & 31, band = t >> 5;
    // chunk 1: output rows 56..111
    if (cq < 28) {
        int j0 = band * 7;
        float4 C[3];
        float L[3], R[3];
        ldrow(sP, j0, cq, C[0], L[0], R[0]);
        ldrow(sP, j0 + 1, cq, C[1], L[1], R[1]);
#pragma unroll
        for (int k = 0; k < 7; k++) {
            int s0 = k % 3, s1i = (k + 1) % 3, s2i = (k + 2) % 3;
            ldrow(sP, j0 + k + 2, cq, C[s2i], L[s2i], R[s2i]);
            float4 o = dw9(C[s0], L[s0], R[s0], C[s1i], L[s1i], R[s1i],
                           C[s2i], L[s2i], R[s2i], myk);
            float4 x1v = C[s1i];
            int row = CHR + j0 + k;
            nt_store4(d1 + (size_t)row * WW + cq * 4, x1v.x * s1v, x1v.y * s1v,
                      x1v.z * s1v, x1v.w * s1v);
            nt_store4(d2 + (size_t)row * WW + cq * 4,
                      fmaxf(o.x + shift2, 0.f) * s2v,
                      fmaxf(o.y + shift2, 0.f) * s2v,
                      fmaxf(o.z + shift2, 0.f) * s2v,
                      fmaxf(o.w + shift2, 0.f) * s2v);
        }
    }
    __syncthreads();
    // restage chunk 0 (x1 rows -1..56): rows 0..55 still pristine, 56 from srow56
    for (int g = t; g < SROWS * 28; g += 256) {
        int r = g / 28, cc = g - r * 28;
        int gr = r - 1;
        float4 v = make_float4(0.f, 0.f, 0.f, 0.f);
        if (gr >= 0 && gr < CHR)
            v = *(const float4*)(d1 + (size_t)gr * WW + (cc << 2));
        else if (gr == CHR)
            v = ((const float4*)srow56)[cc];
        ((float4*)sP)[g] = v;
    }
    __syncthreads();
    // chunk 0: output rows 0..55
    if (cq < 28) {
        int j0 = band * 7;
        float4 C[3];
        float L[3], R[3];
        ldrow(sP, j0, cq, C[0], L[0], R[0]);
        ldrow(sP, j0 + 1, cq, C[1], L[1], R[1]);
#pragma unroll
        for (int k = 0; k < 7; k++) {
            int s0 = k % 3, s1i = (k + 1) % 3, s2i = (k + 2) % 3;
            ldrow(sP, j0 + k + 2, cq, C[s2i], L[s2i], R[s2i]);
            float4 o = dw9(C[s0], L[s0], R[s0], C[s1i], L[s1i], R[s1i],
                           C[s2i], L[s2i], R[s2i], myk);
            float4 x1v = C[s1i];
            int row = j0 + k;
            nt_store4(d1 + (size_t)row * WW + cq * 4, x1v.x * s1v, x1v.y * s1v,
                      x1v.z * s1v, x1v.w * s1v);
            nt_store4(d2 + (size_t)row * WW + cq * 4,
                      fmaxf(o.x + shift2, 0.f) * s2v,
                      fmaxf(o.y + shift2, 0.f) * s2v,
                      fmaxf(o.z + shift2, 0.f) * s2v,
                      fmaxf(o.w + shift2, 0.f) * s2v);
        }
    }
}

extern "C" void kernel_launch(void* const* d_in, const int* in_sizes, int n_in,
                              void* d_out, int out_size, void* d_ws,
                              size_t ws_size, hipStream_t stream) {
    (void)in_sizes; (void)n_in; (void)out_size; (void)ws_size;
    const float* x = (const float*)d_in[0];
    const float* rw1 = (const float*)d_in[1];
    const float* rb1 = (const float*)d_in[2];
    const float* w1 = (const float*)d_in[3];
    const float* bn1_g = (const float*)d_in[4];
    const float* bn1_b = (const float*)d_in[5];
    const float* bn1_m = (const float*)d_in[6];
    const float* bn1_v = (const float*)d_in[7];
    const float* rw2 = (const float*)d_in[8];
    const float* rb2 = (const float*)d_in[9];
    const float* w2 = (const float*)d_in[10];
    const float* bn2_g = (const float*)d_in[11];
    const float* bn2_b = (const float*)d_in[12];
    const float* bn2_m = (const float*)d_in[13];
    const float* bn2_v = (const float*)d_in[14];
    const float* se_w1 = (const float*)d_in[15];
    const float* se_b1 = (const float*)d_in[16];
    const float* se_w2 = (const float*)d_in[17];
    const float* se_b2 = (const float*)d_in[18];
    float* out = (float*)d_out;
    float* ws = (float*)d_ws;
    float* pooled = ws;
    float* sum1 = ws + 1024;
    float* sum2 = ws + 2048;
    float* shift1 = ws + 3072;
    float* k1t = ws + 4096;

    k_pool<<<NB * CIN, 256, 0, stream>>>(x, pooled, sum1);
    k_prep<<<NB, 256, 0, stream>>>(pooled, rw1, rb1, w1, bn1_g, bn1_b, bn1_m,
                                   bn1_v, k1t, shift1);
    k_conv1<<<NB * NT, 256, 0, stream>>>(x, k1t, shift1, out, sum1);
    k_dwsum<<<NB * NEW_C, 256, 0, stream>>>(out, sum1, rw2, rb2, w2, bn2_g,
                                            bn2_b, bn2_m, bn2_v, sum2);
    k_final<<<NB * NEW_C, 256, 0, stream>>>(sum1, sum2, rw2, rb2, w2, bn2_g,
                                            bn2_b, bn2_m, bn2_v, se_w1, se_b1,
                                            se_w2, se_b2, out);
}